// Round 15
// baseline (356.534 us; speedup 1.0000x reference)
//
#include <hip/hip_runtime.h>
#include <stdint.h>
#include <math.h>

#define N_CLS    81
#define TOPK     1000
#define LISTCAP  (1u << 21)     // 2M candidate keys (16 MB)
#define CAP2     16384          // sel2 capacity
#define SCORE_TH 0.05f
#define IMG_W    1333.0f
#define IMG_H    800.0f
#define GH_REP   8              // coarse-hist replicas (atomic spread)

// coarse bucket = float_bits >> 19, range for (0.05, 1.0] is [1961, 2032]
#define GH_BASE  1905           // ghist index = (bits>>19) - GH_BASE, in [56,127]

// workspace layout (byte offsets). Control scalars on separate 128B lines.
#define OFF_CNT    0                       // u32 total candidates
#define OFF_CNT2   128                     // u32 selected count
#define OFF_TICKA  384                     // u32 post-fused-pass ticket
#define OFF_TICKR  640                     // u32 post-rank ticket
#define OFF_GH     1280                    // u32[GH_REP][128] coarse hist (4096 B)
#define OFF_RH     5376                    // u32[1024] refined hist (4096 B)
#define MEMSET_BYTES 9472
#define OFF_SEL    16768                   // u64[LISTCAP]
#define OFF_SEL2   16793984                // u64[CAP2]
#define OFF_BOX    16925056                // u64[1000*2] packed clipped boxes
#define OFF_SCORE  16941056                // u32[1000] score bits
#define OFF_CLS    16945056                // i32[1000]

#define ROWS_PER_BLK 128
#define TILE_FLOATS  (ROWS_PER_BLK * N_CLS)   // 10368 floats = 41472 B (16B-aligned)
#define CBUF_CAP     1024
#define TAIL_BLOCKS  128                   // streaming needs >=128 CUs (r13 lesson)
#define PADK         1016                  // TOPK + TOPK/64 padding for SoA LDS

typedef unsigned long long u64;

__device__ __forceinline__ int ipad(int j) { return j + (j >> 6); }  // bank-spread index

// direct global->LDS 16B DMA (m97 pattern): LDS dest = wave-uniform base + lane*16
__device__ __forceinline__ void gload_lds16(const float* g, float* l) {
    __builtin_amdgcn_global_load_lds(
        (const __attribute__((address_space(1))) unsigned int*)g,
        (__attribute__((address_space(3))) unsigned int*)l, 16, 0, 0);
}

// Device-scope atomics operate at the device coherence point (cross-XCD
// coherent, G12/m20; rounds 8-14 validated drain->ticket->load). NO
// __threadfence(): device fence = per-XCD L2 writeback on gfx950 (poison).
// NO block barriers inside streaming loops (r13 lesson: kills MLP).
__device__ __forceinline__ unsigned agent_load_u32(const unsigned* p) {
    return __hip_atomic_load(p, __ATOMIC_RELAXED, __HIP_MEMORY_SCOPE_AGENT);
}
__device__ __forceinline__ u64 agent_load_u64(const u64* p) {
    return __hip_atomic_load(p, __ATOMIC_RELAXED, __HIP_MEMORY_SCOPE_AGENT);
}
__device__ __forceinline__ void agent_store_u32(unsigned* p, unsigned v) {
    __hip_atomic_store(p, v, __ATOMIC_RELAXED, __HIP_MEMORY_SCOPE_AGENT);
}
__device__ __forceinline__ void agent_store_u64(u64* p, u64 v) {
    __hip_atomic_store(p, v, __ATOMIC_RELAXED, __HIP_MEMORY_SCOPE_AGENT);
}
__device__ __forceinline__ void drain_vm() {
    asm volatile("s_waitcnt vmcnt(0)" ::: "memory");
}

// ------- K1: round-2 pass1 VERBATIM (proven fast; no ticket, no winner work) -------
__global__ __launch_bounds__(256) void k_pass1(
        const float* __restrict__ logits, int nrows,
        u64* __restrict__ sel, unsigned* __restrict__ cnt,
        unsigned* __restrict__ ghist) {
    __shared__ float tile[TILE_FLOATS];
    __shared__ unsigned lh[128];
    __shared__ u64 cbuf[CBUF_CAP];
    __shared__ unsigned lcnt, gbase;
    int tid = threadIdx.x, wv = tid >> 6, ln = tid & 63;
    for (int i = tid; i < 128; i += 256) lh[i] = 0;
    if (tid == 0) lcnt = 0;

    int base = blockIdx.x * ROWS_PER_BLK;
    int nr = nrows - base; if (nr > ROWS_PER_BLK) nr = ROWS_PER_BLK;
    const float* gtile = logits + (size_t)base * N_CLS;

    if (nr == ROWS_PER_BLK) {
        // 10 iterations x 4 waves x 1KB = 40960 B coalesced direct-to-LDS
        #pragma unroll
        for (int it = 0; it < 10; ++it) {
            int c = it * 1024 + wv * 256;          // float offset, wave-uniform
            gload_lds16(gtile + c + ln * 4, tile + c);
        }
        if (tid < TILE_FLOATS - 10240) tile[10240 + tid] = gtile[10240 + tid];
    } else {
        for (int i = tid; i < nr * N_CLS; i += 256) tile[i] = gtile[i];
    }
    __syncthreads();   // drains vmcnt (global_load_lds) + lgkmcnt

    int r = tid >> 1, h = tid & 1;
    if (r < nr) {
        const int rb = r * N_CLS + h;              // first owned class in LDS
        float v[41];
        #pragma unroll
        for (int m = 0; m < 40; ++m) v[m] = tile[rb + 2 * m];
        v[40] = (h == 0) ? tile[rb + 80] : 0.0f;   // class 80 only exists for h=0

        // ---- row max (exact, order-free) ----
        float mx = v[0];
        #pragma unroll
        for (int m = 1; m < 40; ++m) mx = fmaxf(mx, v[m]);
        mx = fmaxf(mx, (h == 0) ? v[40] : v[0]);
        float om = __shfl_xor(mx, 1);
        float mrow = fmaxf(mx, om);

        // ---- exps (op-identical to reference kernel) ----
        #pragma unroll
        for (int m = 0; m < 40; ++m) v[m] = expf(v[m] - mrow);
        v[40] = (h == 0) ? expf(v[40] - mrow) : 0.0f;

        // ---- per-thread bitrev subtree over leaves l = h + 2*b ----
        float stk0 = 0.f, stk1 = 0.f, stk2 = 0.f, stk3 = 0.f, stk4 = 0.f;
        float S = 0.f;
        #pragma unroll
        for (int i = 0; i < 32; ++i) {
            const int b = ((i & 1) << 4) | ((i & 2) << 2) | (i & 4) |
                          ((i & 8) >> 2) | ((i & 16) >> 4);   // bitrev5(i)
            float x = v[b];
            if (b < 8) x += v[b + 32];
            else if (b == 8) x = (h == 0) ? x + v[40] : x;
            if (i & 1) { x = stk0 + x;
              if (i & 2) { x = stk1 + x;
                if (i & 4) { x = stk2 + x;
                  if (i & 8) { x = stk3 + x;
                    if (i & 16) { S = stk4 + x; } else stk4 = x;
                  } else stk3 = x;
                } else stk2 = x;
              } else stk1 = x;
            } else stk0 = x;
        }
        float oS = __shfl_xor(S, 1);
        float s = (h == 0) ? (S + oS) : (oS + S);  // exact top-level association

        // ---- emit: conservative pre-filter, then bit-exact p>0.05 ----
        float eth = 0.0499f * s;                   // 0.2% margin >> fp rounding
        unsigned rowflat = (unsigned)(base + r) * N_CLS + (unsigned)h;
        #pragma unroll
        for (int m = 0; m < 41; ++m) {             // COMPILE-TIME v[] index only
            float e = v[m];
            if ((m + h) != 0 && e > eth) {         // skip background (h=0,m=0)
                float p = e / s;                   // identical division
                if (p > SCORE_TH) {
                    unsigned fb = __float_as_uint(p);
                    atomicAdd(&lh[(fb >> 19) - GH_BASE], 1u);
                    u64 key = ((u64)fb << 32) | (u64)(0xFFFFFFu - (rowflat + 2u * (unsigned)m));
                    unsigned pos = atomicAdd(&lcnt, 1u);
                    if (pos < CBUF_CAP) cbuf[pos] = key;
                    else { unsigned gp = atomicAdd(cnt, 1u); if (gp < LISTCAP) sel[gp] = key; }
                }
            }
        }
    }
    __syncthreads();
    unsigned* gh = ghist + (blockIdx.x & (GH_REP - 1)) * 128;
    for (int i = tid; i < 128; i += 256) {
        unsigned vv = lh[i];
        if (vv) atomicAdd(&gh[i], vv);
    }
    unsigned total = lcnt; if (total > CBUF_CAP) total = CBUF_CAP;
    if (tid == 0) gbase = atomicAdd(cnt, total);
    __syncthreads();
    unsigned gb = gbase;
    for (unsigned i = tid; i < total; i += 256) {
        unsigned gp = gb + i;
        if (gp < LISTCAP) sel[gp] = cbuf[i];
    }
}

// ------- K2: fused tail; post-rank segment = ONE block, registers-only masks -------
// P0/PF/tb/PR verbatim from round 14 (best build). After tickR, blocks 1..127
// exit; block 0 alone: loads boxes into padded-SoA LDS, builds each thread's
// conflict row[16] IN REGISTERS (same-j broadcast reads, conflict-free; no
// global mask round-trip, no extra ticket), then Gauss-Seidel-over-words NMS:
// word w's 64 boxes == wave w, so each wave solves its intra-word triangular
// recurrence with wave-local ballot iteration (no block barriers) given the
// finalized words[<w]; 16 __syncthreads total. Same unique greedy fixed point
// as the verified Jacobi (r14 occupancy math: old 16-block PC+NMS seg ~41us).
__global__ __launch_bounds__(1024) void k_tail(
        char* __restrict__ ws, const float* __restrict__ boxes,
        float* __restrict__ out) {
    unsigned* cnt   = (unsigned*)(ws + OFF_CNT);
    unsigned* cnt2  = (unsigned*)(ws + OFF_CNT2);
    unsigned* tickA = (unsigned*)(ws + OFF_TICKA);
    unsigned* tickR = (unsigned*)(ws + OFF_TICKR);
    unsigned* ghist = (unsigned*)(ws + OFF_GH);
    unsigned* rhist = (unsigned*)(ws + OFF_RH);
    u64*      sel   = (u64*)(ws + OFF_SEL);
    u64*      sel2  = (u64*)(ws + OFF_SEL2);
    u64*      boxB  = (u64*)(ws + OFF_BOX);
    unsigned* scrB  = (unsigned*)(ws + OFF_SCORE);
    unsigned* clsB  = (unsigned*)(ws + OFF_CLS);

    __shared__ unsigned scu[1024], sfu[1024];
    __shared__ union {
        unsigned lhist[1024];               // PF local refine hist (4 KB)
        struct {                            // NMS box cache, bank-padded SoA
            float x1[PADK], y1[PADK], x2[PADK], y2[PADK];
            int cls[PADK]; unsigned sc[PADK];
        } c;                                // ~24.4 KB
    } shu;
    __shared__ u64 words[16];
    __shared__ int swB;
    __shared__ unsigned swCA, stk, stb;

    int tid = threadIdx.x, ln = tid & 63;
    unsigned nb = gridDim.x;

    // -------- P0 (every block, redundant): coarse B, CA from ghist --------
    if (tid < 128) {
        unsigned c = 0;
        #pragma unroll
        for (int rr = 0; rr < GH_REP; ++rr) c += ghist[rr * 128 + tid];  // cross-kernel
        scu[tid] = c; sfu[tid] = c;
    }
    if (tid == 0) swB = -1;
    __syncthreads();
    #pragma unroll
    for (int off = 1; off < 128; off <<= 1) {
        unsigned a = 0;
        if (tid < 128) a = (tid + off < 128) ? sfu[tid + off] : 0u;
        __syncthreads();
        if (tid < 128) sfu[tid] += a;
        __syncthreads();
    }
    if (tid == 0) swCA = sfu[0];                   // total (B<0 fallback)
    __syncthreads();
    if (tid < 128) {
        unsigned incl = sfu[tid], excl = incl - scu[tid];
        if (excl < TOPK && incl >= TOPK) { swB = tid; swCA = excl; }
    }
    __syncthreads();
    int B = swB;
    unsigned CA = swCA;
    unsigned M = *cnt; if (M > LISTCAP) M = LISTCAP;   // cross-kernel plain load
    unsigned stride = nb * 1024u;
    unsigned tbc = (B < 0) ? 0u : ((unsigned)(B + GH_BASE) << 19);  // coarse floor
    unsigned Bbits = (unsigned)(B + GH_BASE);

    // -------- PF: ONE pass: compact >= coarse floor AND refine-histogram.
    // Per-wave cnt2 atomics; NO block barriers inside the loop (r13 lesson). --------
    shu.lhist[tid] = 0;
    __syncthreads();
    for (unsigned ibase = blockIdx.x * 1024u; ibase < M; ibase += stride) {
        unsigned i = ibase + tid;
        bool act = (i < M);
        u64 key = act ? sel[i] : 0ull;                 // cross-kernel plain load
        unsigned bv = (unsigned)(key >> 32);
        if (act && B >= 0 && (bv >> 19) == Bbits)
            atomicAdd(&shu.lhist[(bv >> 9) & 1023u], 1u);
        bool c = act && (bv >= tbc) && (key != 0ull);
        u64 b = __ballot(c);
        int n = __popcll(b);
        if (n) {
            unsigned wb = 0;
            if (ln == 0) wb = atomicAdd(cnt2, (unsigned)n);
            wb = __shfl(wb, 0);
            if (c) {
                unsigned pos = wb + (unsigned)__popcll(b & ((1ull << ln) - 1ull));
                if (pos < CAP2) agent_store_u64(&sel2[pos], key);
            }
        }
    }
    __syncthreads();
    { unsigned vv = shu.lhist[tid]; if (vv) atomicAdd(&rhist[tid], vv); }
    __syncthreads();
    drain_vm();                                        // sel2 + rhist acked
    if (tid == 0) {
        atomicAdd(tickA, 1u);
        unsigned v;
        do { __builtin_amdgcn_s_sleep(2); v = agent_load_u32(tickA); } while (v < nb);
    }
    __syncthreads();

    // -------- tb (every block, redundant): suffix-scan rhist -> exact 512-ULP --------
    unsigned tb = 0;
    {
        unsigned c = (B >= 0) ? agent_load_u32(&rhist[tid]) : 0u;
        scu[tid] = c; sfu[tid] = c;
        if (tid == 0) stb = 0;
        __syncthreads();
        #pragma unroll
        for (int off = 1; off < 1024; off <<= 1) {
            unsigned a = (tid + off < 1024) ? sfu[tid + off] : 0u;
            __syncthreads();
            sfu[tid] += a;
            __syncthreads();
        }
        unsigned incl = sfu[tid], excl = incl - scu[tid];
        if (B >= 0 && CA + excl < TOPK && CA + incl >= TOPK)
            stb = ((unsigned)(B + GH_BASE) << 19) | ((unsigned)tid << 9);
        __syncthreads();
        tb = stb;                                      // 0 when B<0: keep all
    }

    // ---------------- PR: wave-per-key rank + decode (keys >= tb only) ----------------
    {
        unsigned S = agent_load_u32(cnt2); if (S > CAP2) S = CAP2;
        unsigned slot = blockIdx.x * 16u + (unsigned)(tid >> 6);
        unsigned nslots = nb * 16u;                    // 2048 wave-slots
        unsigned lim = (S > TOPK) ? S : TOPK;
        for (unsigned k = slot; k < lim; k += nslots) {
            if (k < S) {
                u64 my = agent_load_u64(&sel2[k]);     // wave-uniform key
                if ((unsigned)(my >> 32) < tb) continue;   // below exact threshold
                unsigned rk = 0;
                for (unsigned j = ln; j < S; j += 64)  // coalesced 512B/wave
                    rk += (agent_load_u64(&sel2[j]) > my) ? 1u : 0u;
                #pragma unroll
                for (int off = 32; off > 0; off >>= 1) rk += __shfl_xor(rk, off);
                if (ln == 0 && rk < TOPK) {
                    float sc = __uint_as_float((unsigned)(my >> 32));
                    unsigned fi = 0xFFFFFFu - (unsigned)(my & 0xFFFFFFFFull);
                    unsigned prop = fi / N_CLS;
                    int cls = (int)(fi - prop * N_CLS);
                    const float* bx = boxes + (size_t)prop * 4;
                    float x1 = fminf(fmaxf(bx[0], 0.0f), IMG_W - 1.0f);
                    float y1 = fminf(fmaxf(bx[1], 0.0f), IMG_H - 1.0f);
                    float x2 = fminf(fmaxf(bx[2], 0.0f), IMG_W - 1.0f);
                    float y2 = fminf(fmaxf(bx[3], 0.0f), IMG_H - 1.0f);
                    agent_store_u64(&boxB[rk * 2],
                        ((u64)__float_as_uint(y1) << 32) | __float_as_uint(x1));
                    agent_store_u64(&boxB[rk * 2 + 1],
                        ((u64)__float_as_uint(y2) << 32) | __float_as_uint(x2));
                    agent_store_u32(&scrB[rk], __float_as_uint(sc));
                    agent_store_u32(&clsB[rk], (unsigned)cls);
                }
            } else if (ln == 0) {                      // k in [S, TOPK): B<0 defaults
                agent_store_u64(&boxB[k * 2], 0ull);
                agent_store_u64(&boxB[k * 2 + 1], 0ull);
                agent_store_u32(&scrB[k], 0u);
                agent_store_u32(&clsB[k], (unsigned)-1);
            }
        }
    }
    __syncthreads();
    drain_vm();
    if (tid == 0) stk = atomicAdd(tickR, 1u);
    __syncthreads();
    if (blockIdx.x != 0) return;                       // all other blocks exit
    if (tid == 0) {
        unsigned v;
        do { __builtin_amdgcn_s_sleep(2); v = agent_load_u32(tickR); } while (v < nb);
    }
    __syncthreads();

    // -------- single-block: load boxes into padded SoA LDS --------
    if (tid < TOPK) {
        u64 a = agent_load_u64(&boxB[tid * 2]);
        u64 b = agent_load_u64(&boxB[tid * 2 + 1]);
        int ip = ipad(tid);
        shu.c.x1[ip] = __uint_as_float((unsigned)a);
        shu.c.y1[ip] = __uint_as_float((unsigned)(a >> 32));
        shu.c.x2[ip] = __uint_as_float((unsigned)b);
        shu.c.y2[ip] = __uint_as_float((unsigned)(b >> 32));
        shu.c.cls[ip] = (int)agent_load_u32(&clsB[tid]);
        shu.c.sc[ip]  = agent_load_u32(&scrB[tid]);
    }
    __syncthreads();

    // -------- conflict row[16] in REGISTERS (thread tid == box tid) --------
    // All threads read the same j each step -> LDS broadcast, conflict-free.
    u64 row[16];
    {
        int ip = ipad(tid < TOPK ? tid : 0);
        float x1 = shu.c.x1[ip], y1 = shu.c.y1[ip];
        float x2 = shu.c.x2[ip], y2 = shu.c.y2[ip];
        int ci = shu.c.cls[ip];
        float ai = (x2 - x1) * (y2 - y1);
        #pragma unroll
        for (int w = 0; w < 16; ++w) {
            u64 m = 0;
            int jbase = w << 6;
            for (int jj = 0; jj < 64; jj++) {
                int j = jbase + jj;
                if (j >= TOPK) break;
                int jp = ipad(j);
                float u1 = shu.c.x1[jp], w1 = shu.c.y1[jp];
                float u2 = shu.c.x2[jp], w2 = shu.c.y2[jp];
                float aj = (u2 - u1) * (w2 - w1);
                float ww = fmaxf(fminf(x2, u2) - fmaxf(x1, u1), 0.0f);
                float hh = fmaxf(fminf(y2, w2) - fmaxf(y1, w1), 0.0f);
                float inter = ww * hh;
                float iou = inter / (ai + aj - inter + 1e-9f);
                if (iou > 0.5f && ci == shu.c.cls[jp]) m |= (1ull << jj);
            }
            row[w] = (tid < TOPK) ? m : 0ull;
        }
    }

    // -------- Gauss-Seidel-over-words NMS: wave w == word w --------
    // keep[i] = valid[i] & !OR_{j<i}(keep[j] & conflict[j][i]); conflict is
    // symmetric, so keep[j]&conf[j][i] = keep[j]&row_i bit j. Earlier words
    // finalized exactly; intra-word fixed point via wave-local ballot loop.
    int wvv = tid >> 6;
    int myip = ipad(tid < TOPK ? tid : 0);
    bool valid = (tid < TOPK) && (__uint_as_float(shu.c.sc[myip]) > 0.0f);
    u64 lowmask = (1ull << ln) - 1ull;
    bool keep = false;
    for (int w = 0; w < 16; ++w) {
        if (wvv == w) {
            u64 ext = 0;
            for (int u = 0; u < w; ++u) ext |= row[u] & words[u];   // finalized
            bool k = valid && (ext == 0ull);
            u64 K = __ballot(k), Kp;
            int guard = 0;
            do {
                Kp = K;
                k = valid && (ext == 0ull) && ((row[w] & Kp & lowmask) == 0ull);
                K = __ballot(k);
            } while (K != Kp && ++guard < 64);
            if (ln == 0) words[w] = K;
            keep = k;
        }
        __syncthreads();                               // publish words[w]
    }

    if (tid < TOPK) {
        float sc = __uint_as_float(shu.c.sc[myip]);
        out[tid * 5 + 0] = keep ? shu.c.x1[myip] : 0.0f;
        out[tid * 5 + 1] = keep ? shu.c.y1[myip] : 0.0f;
        out[tid * 5 + 2] = keep ? shu.c.x2[myip] : 0.0f;
        out[tid * 5 + 3] = keep ? shu.c.y2[myip] : 0.0f;
        out[tid * 5 + 4] = keep ? sc : 0.0f;
    }
}

extern "C" void kernel_launch(void* const* d_in, const int* in_sizes, int n_in,
                              void* d_out, int out_size, void* d_ws, size_t ws_size,
                              hipStream_t stream) {
    const float* logits = (const float*)d_in[0];
    const float* boxes  = (const float*)d_in[1];
    float* out = (float*)d_out;
    int nrows = in_sizes[0] / N_CLS;   // 200000

    char* w = (char*)d_ws;
    unsigned* cnt   = (unsigned*)(w + OFF_CNT);
    unsigned* ghist = (unsigned*)(w + OFF_GH);
    u64* sel        = (u64*)(w + OFF_SEL);

    hipMemsetAsync(w, 0, MEMSET_BYTES, stream);

    int nblk = (nrows + ROWS_PER_BLK - 1) / ROWS_PER_BLK;   // 1563
    k_pass1<<<nblk, 256, 0, stream>>>(logits, nrows, sel, cnt, ghist);
    k_tail<<<TAIL_BLOCKS, 1024, 0, stream>>>(w, boxes, out);
}

// Round 16
// 192.022 us; speedup vs baseline: 1.8567x; 1.8567x over previous
//
#include <hip/hip_runtime.h>
#include <stdint.h>
#include <math.h>

#define N_CLS    81
#define TOPK     1000
#define LISTCAP  (1u << 21)     // 2M candidate keys (16 MB)
#define CAP2     16384          // sel2 capacity
#define SCORE_TH 0.05f
#define IMG_W    1333.0f
#define IMG_H    800.0f
#define GH_REP   8              // coarse-hist replicas (atomic spread)

// coarse bucket = float_bits >> 19, range for (0.05, 1.0] is [1961, 2032]
#define GH_BASE  1905           // ghist index = (bits>>19) - GH_BASE, in [56,127]

// workspace layout (byte offsets). Control scalars on separate 128B lines.
#define OFF_CNT    0                       // u32 total candidates
#define OFF_CNT2   128                     // u32 selected count
#define OFF_TICKA  384                     // u32 post-fused-pass ticket
#define OFF_TICKR  640                     // u32 post-rank ticket
#define OFF_TICKC  768                     // u32 mask ticket
#define OFF_GH     1280                    // u32[GH_REP][128] coarse hist (4096 B)
#define OFF_RH     5376                    // u32[1024] refined hist (4096 B)
#define MEMSET_BYTES 9472
#define OFF_SEL    16768                   // u64[LISTCAP]
#define OFF_SEL2   16793984                // u64[CAP2]
#define OFF_BOX    16925056                // u64[1000*2] packed clipped boxes
#define OFF_SCORE  16941056                // u32[1000] score bits
#define OFF_CLS    16945056                // i32[1000]
#define OFF_MASK   16949056                // u64[1000*16] conflict bit matrix

#define ROWS_PER_BLK 96                    // 31.1 KB tile -> 4 blocks/CU (was 3)
#define TILE_FLOATS  (ROWS_PER_BLK * N_CLS)   // 7776 floats = 31104 B (16B-aligned)
#define CBUF_CAP     768                   // avg ~437 cand/96-row block; spill path exists
#define TAIL_BLOCKS  128                   // streaming needs >=128 CUs (r13 lesson)
#define PADK         1016                  // TOPK + TOPK/64 padding for SoA LDS

typedef unsigned long long u64;

__device__ __forceinline__ int ipad(int j) { return j + (j >> 6); }  // bank-spread index

// direct global->LDS 16B DMA (m97 pattern): LDS dest = wave-uniform base + lane*16
__device__ __forceinline__ void gload_lds16(const float* g, float* l) {
    __builtin_amdgcn_global_load_lds(
        (const __attribute__((address_space(1))) unsigned int*)g,
        (__attribute__((address_space(3))) unsigned int*)l, 16, 0, 0);
}

// Device-scope atomics operate at the device coherence point (cross-XCD
// coherent, G12/m20; rounds 8-14 validated drain->ticket->load). NO
// __threadfence(): device fence = per-XCD L2 writeback on gfx950 (poison).
// NO block barriers inside streaming loops (r13); NO single-block O(K^2)
// phases (r15: 1M IoU on one CU = 70us).
__device__ __forceinline__ unsigned agent_load_u32(const unsigned* p) {
    return __hip_atomic_load(p, __ATOMIC_RELAXED, __HIP_MEMORY_SCOPE_AGENT);
}
__device__ __forceinline__ u64 agent_load_u64(const u64* p) {
    return __hip_atomic_load(p, __ATOMIC_RELAXED, __HIP_MEMORY_SCOPE_AGENT);
}
__device__ __forceinline__ void agent_store_u32(unsigned* p, unsigned v) {
    __hip_atomic_store(p, v, __ATOMIC_RELAXED, __HIP_MEMORY_SCOPE_AGENT);
}
__device__ __forceinline__ void agent_store_u64(u64* p, u64 v) {
    __hip_atomic_store(p, v, __ATOMIC_RELAXED, __HIP_MEMORY_SCOPE_AGENT);
}
__device__ __forceinline__ void drain_vm() {
    asm volatile("s_waitcnt vmcnt(0)" ::: "memory");
}

// ------- K1: round-2 pass1, 96-row tile (4 blocks/CU). Math VERBATIM. -------
__global__ __launch_bounds__(256) void k_pass1(
        const float* __restrict__ logits, int nrows,
        u64* __restrict__ sel, unsigned* __restrict__ cnt,
        unsigned* __restrict__ ghist) {
    __shared__ float tile[TILE_FLOATS];
    __shared__ unsigned lh[128];
    __shared__ u64 cbuf[CBUF_CAP];
    __shared__ unsigned lcnt, gbase;
    int tid = threadIdx.x, wv = tid >> 6, ln = tid & 63;
    for (int i = tid; i < 128; i += 256) lh[i] = 0;
    if (tid == 0) lcnt = 0;

    int base = blockIdx.x * ROWS_PER_BLK;
    int nr = nrows - base; if (nr > ROWS_PER_BLK) nr = ROWS_PER_BLK;
    const float* gtile = logits + (size_t)base * N_CLS;

    if (nr == ROWS_PER_BLK) {
        // 7 iterations x 4 waves x 1KB = 28672 B direct-to-LDS + 608-float tail
        #pragma unroll
        for (int it = 0; it < 7; ++it) {
            int c = it * 1024 + wv * 256;          // float offset, wave-uniform
            gload_lds16(gtile + c + ln * 4, tile + c);
        }
        for (int i = 7168 + tid; i < TILE_FLOATS; i += 256) tile[i] = gtile[i];
    } else {
        for (int i = tid; i < nr * N_CLS; i += 256) tile[i] = gtile[i];
    }
    __syncthreads();   // drains vmcnt (global_load_lds) + lgkmcnt

    int r = tid >> 1, h = tid & 1;
    if (r < nr) {
        const int rb = r * N_CLS + h;              // first owned class in LDS
        float v[41];
        #pragma unroll
        for (int m = 0; m < 40; ++m) v[m] = tile[rb + 2 * m];
        v[40] = (h == 0) ? tile[rb + 80] : 0.0f;   // class 80 only exists for h=0

        // ---- row max (exact, order-free) ----
        float mx = v[0];
        #pragma unroll
        for (int m = 1; m < 40; ++m) mx = fmaxf(mx, v[m]);
        mx = fmaxf(mx, (h == 0) ? v[40] : v[0]);
        float om = __shfl_xor(mx, 1);
        float mrow = fmaxf(mx, om);

        // ---- exps (op-identical to reference kernel) ----
        #pragma unroll
        for (int m = 0; m < 40; ++m) v[m] = expf(v[m] - mrow);
        v[40] = (h == 0) ? expf(v[40] - mrow) : 0.0f;

        // ---- per-thread bitrev subtree over leaves l = h + 2*b ----
        float stk0 = 0.f, stk1 = 0.f, stk2 = 0.f, stk3 = 0.f, stk4 = 0.f;
        float S = 0.f;
        #pragma unroll
        for (int i = 0; i < 32; ++i) {
            const int b = ((i & 1) << 4) | ((i & 2) << 2) | (i & 4) |
                          ((i & 8) >> 2) | ((i & 16) >> 4);   // bitrev5(i)
            float x = v[b];
            if (b < 8) x += v[b + 32];
            else if (b == 8) x = (h == 0) ? x + v[40] : x;
            if (i & 1) { x = stk0 + x;
              if (i & 2) { x = stk1 + x;
                if (i & 4) { x = stk2 + x;
                  if (i & 8) { x = stk3 + x;
                    if (i & 16) { S = stk4 + x; } else stk4 = x;
                  } else stk3 = x;
                } else stk2 = x;
              } else stk1 = x;
            } else stk0 = x;
        }
        float oS = __shfl_xor(S, 1);
        float s = (h == 0) ? (S + oS) : (oS + S);  // exact top-level association

        // ---- emit: conservative pre-filter, then bit-exact p>0.05 ----
        float eth = 0.0499f * s;                   // 0.2% margin >> fp rounding
        unsigned rowflat = (unsigned)(base + r) * N_CLS + (unsigned)h;
        #pragma unroll
        for (int m = 0; m < 41; ++m) {             // COMPILE-TIME v[] index only
            float e = v[m];
            if ((m + h) != 0 && e > eth) {         // skip background (h=0,m=0)
                float p = e / s;                   // identical division
                if (p > SCORE_TH) {
                    unsigned fb = __float_as_uint(p);
                    atomicAdd(&lh[(fb >> 19) - GH_BASE], 1u);
                    u64 key = ((u64)fb << 32) | (u64)(0xFFFFFFu - (rowflat + 2u * (unsigned)m));
                    unsigned pos = atomicAdd(&lcnt, 1u);
                    if (pos < CBUF_CAP) cbuf[pos] = key;
                    else { unsigned gp = atomicAdd(cnt, 1u); if (gp < LISTCAP) sel[gp] = key; }
                }
            }
        }
    }
    __syncthreads();
    unsigned* gh = ghist + (blockIdx.x & (GH_REP - 1)) * 128;
    for (int i = tid; i < 128; i += 256) {
        unsigned vv = lh[i];
        if (vv) atomicAdd(&gh[i], vv);
    }
    unsigned total = lcnt; if (total > CBUF_CAP) total = CBUF_CAP;
    if (tid == 0) gbase = atomicAdd(cnt, total);
    __syncthreads();
    unsigned gb = gbase;
    for (unsigned i = tid; i < total; i += 256) {
        unsigned gp = gb + i;
        if (gp < LISTCAP) sel[gp] = cbuf[i];
    }
}

// ------- K2: fused tail. PC masks spread over ALL 128 blocks; GS-NMS winner -------
// P0/PF/tb/PR verbatim from round 14 (184.7us anchor). Post-tickR: every block
// coop-loads the 1000 boxes into padded-SoA LDS (1 load/thread), threads 0..127
// compute an 8-box x 16-word mask slice (128 tasks/block x 128 blocks >= 16000;
// r15 lesson: never one block for the O(K^2) phase). Last tickC arrival runs
// the r15-VERIFIED Gauss-Seidel-over-words NMS (16 barriers, not ~2x60).
__global__ __launch_bounds__(1024) void k_tail(
        char* __restrict__ ws, const float* __restrict__ boxes,
        float* __restrict__ out) {
    unsigned* cnt   = (unsigned*)(ws + OFF_CNT);
    unsigned* cnt2  = (unsigned*)(ws + OFF_CNT2);
    unsigned* tickA = (unsigned*)(ws + OFF_TICKA);
    unsigned* tickR = (unsigned*)(ws + OFF_TICKR);
    unsigned* tickC = (unsigned*)(ws + OFF_TICKC);
    unsigned* ghist = (unsigned*)(ws + OFF_GH);
    unsigned* rhist = (unsigned*)(ws + OFF_RH);
    u64*      sel   = (u64*)(ws + OFF_SEL);
    u64*      sel2  = (u64*)(ws + OFF_SEL2);
    u64*      boxB  = (u64*)(ws + OFF_BOX);
    unsigned* scrB  = (unsigned*)(ws + OFF_SCORE);
    unsigned* clsB  = (unsigned*)(ws + OFF_CLS);
    u64*      mask  = (u64*)(ws + OFF_MASK);

    __shared__ unsigned scu[1024], sfu[1024];
    __shared__ union {
        unsigned lhist[1024];               // PF local refine hist (4 KB)
        struct {                            // box cache, bank-padded SoA
            float x1[PADK], y1[PADK], x2[PADK], y2[PADK];
            int cls[PADK]; unsigned sc[PADK];
        } c;                                // ~24.4 KB
    } shu;
    __shared__ u64 words[16];
    __shared__ int swB;
    __shared__ unsigned swCA, stk, stb;

    int tid = threadIdx.x, ln = tid & 63;
    unsigned nb = gridDim.x;

    // -------- P0 (every block, redundant): coarse B, CA from ghist --------
    if (tid < 128) {
        unsigned c = 0;
        #pragma unroll
        for (int rr = 0; rr < GH_REP; ++rr) c += ghist[rr * 128 + tid];  // cross-kernel
        scu[tid] = c; sfu[tid] = c;
    }
    if (tid == 0) swB = -1;
    __syncthreads();
    #pragma unroll
    for (int off = 1; off < 128; off <<= 1) {
        unsigned a = 0;
        if (tid < 128) a = (tid + off < 128) ? sfu[tid + off] : 0u;
        __syncthreads();
        if (tid < 128) sfu[tid] += a;
        __syncthreads();
    }
    if (tid == 0) swCA = sfu[0];                   // total (B<0 fallback)
    __syncthreads();
    if (tid < 128) {
        unsigned incl = sfu[tid], excl = incl - scu[tid];
        if (excl < TOPK && incl >= TOPK) { swB = tid; swCA = excl; }
    }
    __syncthreads();
    int B = swB;
    unsigned CA = swCA;
    unsigned M = *cnt; if (M > LISTCAP) M = LISTCAP;   // cross-kernel plain load
    unsigned stride = nb * 1024u;
    unsigned tbc = (B < 0) ? 0u : ((unsigned)(B + GH_BASE) << 19);  // coarse floor
    unsigned Bbits = (unsigned)(B + GH_BASE);

    // -------- PF: ONE pass: compact >= coarse floor AND refine-histogram.
    // Per-wave cnt2 atomics; NO block barriers inside the loop (r13 lesson). --------
    shu.lhist[tid] = 0;
    __syncthreads();
    for (unsigned ibase = blockIdx.x * 1024u; ibase < M; ibase += stride) {
        unsigned i = ibase + tid;
        bool act = (i < M);
        u64 key = act ? sel[i] : 0ull;                 // cross-kernel plain load
        unsigned bv = (unsigned)(key >> 32);
        if (act && B >= 0 && (bv >> 19) == Bbits)
            atomicAdd(&shu.lhist[(bv >> 9) & 1023u], 1u);
        bool c = act && (bv >= tbc) && (key != 0ull);
        u64 b = __ballot(c);
        int n = __popcll(b);
        if (n) {
            unsigned wb = 0;
            if (ln == 0) wb = atomicAdd(cnt2, (unsigned)n);
            wb = __shfl(wb, 0);
            if (c) {
                unsigned pos = wb + (unsigned)__popcll(b & ((1ull << ln) - 1ull));
                if (pos < CAP2) agent_store_u64(&sel2[pos], key);
            }
        }
    }
    __syncthreads();
    { unsigned vv = shu.lhist[tid]; if (vv) atomicAdd(&rhist[tid], vv); }
    __syncthreads();
    drain_vm();                                        // sel2 + rhist acked
    if (tid == 0) {
        atomicAdd(tickA, 1u);
        unsigned v;
        do { __builtin_amdgcn_s_sleep(2); v = agent_load_u32(tickA); } while (v < nb);
    }
    __syncthreads();

    // -------- tb (every block, redundant): suffix-scan rhist -> exact 512-ULP --------
    unsigned tb = 0;
    {
        unsigned c = (B >= 0) ? agent_load_u32(&rhist[tid]) : 0u;
        scu[tid] = c; sfu[tid] = c;
        if (tid == 0) stb = 0;
        __syncthreads();
        #pragma unroll
        for (int off = 1; off < 1024; off <<= 1) {
            unsigned a = (tid + off < 1024) ? sfu[tid + off] : 0u;
            __syncthreads();
            sfu[tid] += a;
            __syncthreads();
        }
        unsigned incl = sfu[tid], excl = incl - scu[tid];
        if (B >= 0 && CA + excl < TOPK && CA + incl >= TOPK)
            stb = ((unsigned)(B + GH_BASE) << 19) | ((unsigned)tid << 9);
        __syncthreads();
        tb = stb;                                      // 0 when B<0: keep all
    }

    // ---------------- PR: wave-per-key rank + decode (keys >= tb only) ----------------
    {
        unsigned S = agent_load_u32(cnt2); if (S > CAP2) S = CAP2;
        unsigned slot = blockIdx.x * 16u + (unsigned)(tid >> 6);
        unsigned nslots = nb * 16u;                    // 2048 wave-slots
        unsigned lim = (S > TOPK) ? S : TOPK;
        for (unsigned k = slot; k < lim; k += nslots) {
            if (k < S) {
                u64 my = agent_load_u64(&sel2[k]);     // wave-uniform key
                if ((unsigned)(my >> 32) < tb) continue;   // below exact threshold
                unsigned rk = 0;
                for (unsigned j = ln; j < S; j += 64)  // coalesced 512B/wave
                    rk += (agent_load_u64(&sel2[j]) > my) ? 1u : 0u;
                #pragma unroll
                for (int off = 32; off > 0; off >>= 1) rk += __shfl_xor(rk, off);
                if (ln == 0 && rk < TOPK) {
                    float sc = __uint_as_float((unsigned)(my >> 32));
                    unsigned fi = 0xFFFFFFu - (unsigned)(my & 0xFFFFFFFFull);
                    unsigned prop = fi / N_CLS;
                    int cls = (int)(fi - prop * N_CLS);
                    const float* bx = boxes + (size_t)prop * 4;
                    float x1 = fminf(fmaxf(bx[0], 0.0f), IMG_W - 1.0f);
                    float y1 = fminf(fmaxf(bx[1], 0.0f), IMG_H - 1.0f);
                    float x2 = fminf(fmaxf(bx[2], 0.0f), IMG_W - 1.0f);
                    float y2 = fminf(fmaxf(bx[3], 0.0f), IMG_H - 1.0f);
                    agent_store_u64(&boxB[rk * 2],
                        ((u64)__float_as_uint(y1) << 32) | __float_as_uint(x1));
                    agent_store_u64(&boxB[rk * 2 + 1],
                        ((u64)__float_as_uint(y2) << 32) | __float_as_uint(x2));
                    agent_store_u32(&scrB[rk], __float_as_uint(sc));
                    agent_store_u32(&clsB[rk], (unsigned)cls);
                }
            } else if (ln == 0) {                      // k in [S, TOPK): B<0 defaults
                agent_store_u64(&boxB[k * 2], 0ull);
                agent_store_u64(&boxB[k * 2 + 1], 0ull);
                agent_store_u32(&scrB[k], 0u);
                agent_store_u32(&clsB[k], (unsigned)-1);
            }
        }
    }
    __syncthreads();
    drain_vm();
    if (tid == 0) {
        atomicAdd(tickR, 1u);
        unsigned v;
        do { __builtin_amdgcn_s_sleep(2); v = agent_load_u32(tickR); } while (v < nb);
    }
    __syncthreads();

    // -------- PC (ALL blocks): coop-load boxes to LDS; 8-box mask slice --------
    if (tid < TOPK) {
        u64 a = agent_load_u64(&boxB[tid * 2]);
        u64 b = agent_load_u64(&boxB[tid * 2 + 1]);
        int ip = ipad(tid);
        shu.c.x1[ip] = __uint_as_float((unsigned)a);
        shu.c.y1[ip] = __uint_as_float((unsigned)(a >> 32));
        shu.c.x2[ip] = __uint_as_float((unsigned)b);
        shu.c.y2[ip] = __uint_as_float((unsigned)(b >> 32));
        shu.c.cls[ip] = (int)agent_load_u32(&clsB[tid]);
        shu.c.sc[ip]  = agent_load_u32(&scrB[tid]);
    }
    __syncthreads();
    if (tid < 128) {
        int i = blockIdx.x * 8 + (tid >> 4), w = tid & 15;
        if (i < TOPK) {
            int ip = ipad(i);
            float x1 = shu.c.x1[ip], y1 = shu.c.y1[ip];
            float x2 = shu.c.x2[ip], y2 = shu.c.y2[ip];
            int ci = shu.c.cls[ip];
            float ai = (x2 - x1) * (y2 - y1);
            u64 m = 0;
            int jbase = w << 6;
            for (int jj = 0; jj < 64; jj++) {
                int j = jbase + jj;
                if (j >= TOPK) break;
                int jp = ipad(j);                      // stride-65: conflict-free
                float u1 = shu.c.x1[jp], w1 = shu.c.y1[jp];
                float u2 = shu.c.x2[jp], w2 = shu.c.y2[jp];
                float aj = (u2 - u1) * (w2 - w1);
                float ww = fmaxf(fminf(x2, u2) - fmaxf(x1, u1), 0.0f);
                float hh = fmaxf(fminf(y2, w2) - fmaxf(y1, w1), 0.0f);
                float inter = ww * hh;
                float iou = inter / (ai + aj - inter + 1e-9f);
                if (iou > 0.5f && ci == shu.c.cls[jp]) m |= (1ull << jj);
            }
            agent_store_u64(&mask[(size_t)i * 16 + w], m);
        }
    }
    __syncthreads();
    drain_vm();
    if (tid == 0) stk = atomicAdd(tickC, 1u);
    __syncthreads();
    if (stk != nb - 1) return;                         // last arrival runs NMS

    // -------- winner: Gauss-Seidel-over-words NMS (r15-verified logic) --------
    // keep[i] = valid[i] & !OR_{j<i}(keep[j] & conflict[j][i]); conflict
    // symmetric. Words finalized in order; intra-word fixed point via
    // wave-local ballot loop (unique fixed point of triangular recurrence).
    u64 row[16];
    #pragma unroll
    for (int w = 0; w < 16; w++)
        row[w] = (tid < TOPK) ? agent_load_u64(&mask[(size_t)tid * 16 + w]) : 0ull;
    int wvv = tid >> 6;
    int myip = ipad(tid < TOPK ? tid : 0);
    bool valid = (tid < TOPK) && (__uint_as_float(shu.c.sc[myip]) > 0.0f);
    u64 lowmask = (1ull << ln) - 1ull;
    bool keep = false;
    for (int w = 0; w < 16; ++w) {
        if (wvv == w) {
            u64 ext = 0;
            for (int u = 0; u < w; ++u) ext |= row[u] & words[u];   // finalized
            bool k = valid && (ext == 0ull);
            u64 K = __ballot(k), Kp;
            int guard = 0;
            do {
                Kp = K;
                k = valid && (ext == 0ull) && ((row[w] & Kp & lowmask) == 0ull);
                K = __ballot(k);
            } while (K != Kp && ++guard < 64);
            if (ln == 0) words[w] = K;
            keep = k;
        }
        __syncthreads();                               // publish words[w]
    }

    if (tid < TOPK) {
        float sc = __uint_as_float(shu.c.sc[myip]);
        out[tid * 5 + 0] = keep ? shu.c.x1[myip] : 0.0f;
        out[tid * 5 + 1] = keep ? shu.c.y1[myip] : 0.0f;
        out[tid * 5 + 2] = keep ? shu.c.x2[myip] : 0.0f;
        out[tid * 5 + 3] = keep ? shu.c.y2[myip] : 0.0f;
        out[tid * 5 + 4] = keep ? sc : 0.0f;
    }
}

extern "C" void kernel_launch(void* const* d_in, const int* in_sizes, int n_in,
                              void* d_out, int out_size, void* d_ws, size_t ws_size,
                              hipStream_t stream) {
    const float* logits = (const float*)d_in[0];
    const float* boxes  = (const float*)d_in[1];
    float* out = (float*)d_out;
    int nrows = in_sizes[0] / N_CLS;   // 200000

    char* w = (char*)d_ws;
    unsigned* cnt   = (unsigned*)(w + OFF_CNT);
    unsigned* ghist = (unsigned*)(w + OFF_GH);
    u64* sel        = (u64*)(w + OFF_SEL);

    hipMemsetAsync(w, 0, MEMSET_BYTES, stream);

    int nblk = (nrows + ROWS_PER_BLK - 1) / ROWS_PER_BLK;   // 2084
    k_pass1<<<nblk, 256, 0, stream>>>(logits, nrows, sel, cnt, ghist);
    k_tail<<<TAIL_BLOCKS, 1024, 0, stream>>>(w, boxes, out);
}

// Round 17
// 182.535 us; speedup vs baseline: 1.9532x; 1.0520x over previous
//
#include <hip/hip_runtime.h>
#include <stdint.h>
#include <math.h>

#define N_CLS    81
#define TOPK     1000
#define LISTCAP  (1u << 21)     // 2M candidate keys (16 MB)
#define CAP2     16384          // sel2 capacity
#define SCORE_TH 0.05f
#define IMG_W    1333.0f
#define IMG_H    800.0f
#define GH_REP   8              // coarse-hist replicas (atomic spread)

// coarse bucket = float_bits >> 19, range for (0.05, 1.0] is [1961, 2032]
#define GH_BASE  1905           // ghist index = (bits>>19) - GH_BASE, in [56,127]

// workspace layout (byte offsets). Control scalars on separate 128B lines.
#define OFF_CNT    0                       // u32 total candidates
#define OFF_CNT2   128                     // u32 selected count
#define OFF_TICKA  384                     // u32 post-fused-pass ticket
#define OFF_TICKR  640                     // u32 post-rank ticket
#define OFF_TICKC  768                     // u32 mask ticket
#define OFF_GH     1280                    // u32[GH_REP][128] coarse hist (4096 B)
#define OFF_RH     5376                    // u32[1024] refined hist (4096 B)
#define MEMSET_BYTES 9472
#define OFF_SEL    16768                   // u64[LISTCAP]
#define OFF_SEL2   16793984                // u64[CAP2]
#define OFF_BOX    16925056                // u64[1000*2] packed clipped boxes
#define OFF_SCORE  16941056                // u32[1000] score bits
#define OFF_CLS    16945056                // i32[1000]
#define OFF_MASK   16949056                // u64[1000*16] conflict bit matrix

#define ROWS_PER_BLK 128                   // r16 lesson: 96-row tile REGRESSED pass1
#define TILE_FLOATS  (ROWS_PER_BLK * N_CLS)   // 10368 floats = 41472 B (16B-aligned)
#define CBUF_CAP     1024
#define TAIL_BLOCKS  128                   // streaming needs >=128 CUs (r13 lesson)
#define PADK         1016                  // TOPK + TOPK/64 padding for SoA LDS

typedef unsigned long long u64;

__device__ __forceinline__ int ipad(int j) { return j + (j >> 6); }  // bank-spread index

// direct global->LDS 16B DMA (m97 pattern): LDS dest = wave-uniform base + lane*16
__device__ __forceinline__ void gload_lds16(const float* g, float* l) {
    __builtin_amdgcn_global_load_lds(
        (const __attribute__((address_space(1))) unsigned int*)g,
        (__attribute__((address_space(3))) unsigned int*)l, 16, 0, 0);
}

// Device-scope atomics operate at the device coherence point (cross-XCD
// coherent, G12/m20; rounds 8-16 validated drain->ticket->load). NO
// __threadfence(): device fence = per-XCD L2 writeback on gfx950 (poison).
// NO block barriers inside streaming loops (r13); NO single-block O(K^2)
// phases (r15).
__device__ __forceinline__ unsigned agent_load_u32(const unsigned* p) {
    return __hip_atomic_load(p, __ATOMIC_RELAXED, __HIP_MEMORY_SCOPE_AGENT);
}
__device__ __forceinline__ u64 agent_load_u64(const u64* p) {
    return __hip_atomic_load(p, __ATOMIC_RELAXED, __HIP_MEMORY_SCOPE_AGENT);
}
__device__ __forceinline__ void agent_store_u32(unsigned* p, unsigned v) {
    __hip_atomic_store(p, v, __ATOMIC_RELAXED, __HIP_MEMORY_SCOPE_AGENT);
}
__device__ __forceinline__ void agent_store_u64(u64* p, u64 v) {
    __hip_atomic_store(p, v, __ATOMIC_RELAXED, __HIP_MEMORY_SCOPE_AGENT);
}
__device__ __forceinline__ void drain_vm() {
    asm volatile("s_waitcnt vmcnt(0)" ::: "memory");
}

// ------- K1: round-2/14 pass1 VERBATIM (128-row tile, VGPR-68 config) -------
__global__ __launch_bounds__(256) void k_pass1(
        const float* __restrict__ logits, int nrows,
        u64* __restrict__ sel, unsigned* __restrict__ cnt,
        unsigned* __restrict__ ghist) {
    __shared__ float tile[TILE_FLOATS];
    __shared__ unsigned lh[128];
    __shared__ u64 cbuf[CBUF_CAP];
    __shared__ unsigned lcnt, gbase;
    int tid = threadIdx.x, wv = tid >> 6, ln = tid & 63;
    for (int i = tid; i < 128; i += 256) lh[i] = 0;
    if (tid == 0) lcnt = 0;

    int base = blockIdx.x * ROWS_PER_BLK;
    int nr = nrows - base; if (nr > ROWS_PER_BLK) nr = ROWS_PER_BLK;
    const float* gtile = logits + (size_t)base * N_CLS;

    if (nr == ROWS_PER_BLK) {
        // 10 iterations x 4 waves x 1KB = 40960 B coalesced direct-to-LDS
        #pragma unroll
        for (int it = 0; it < 10; ++it) {
            int c = it * 1024 + wv * 256;          // float offset, wave-uniform
            gload_lds16(gtile + c + ln * 4, tile + c);
        }
        if (tid < TILE_FLOATS - 10240) tile[10240 + tid] = gtile[10240 + tid];
    } else {
        for (int i = tid; i < nr * N_CLS; i += 256) tile[i] = gtile[i];
    }
    __syncthreads();   // drains vmcnt (global_load_lds) + lgkmcnt

    int r = tid >> 1, h = tid & 1;
    if (r < nr) {
        const int rb = r * N_CLS + h;              // first owned class in LDS
        float v[41];
        #pragma unroll
        for (int m = 0; m < 40; ++m) v[m] = tile[rb + 2 * m];
        v[40] = (h == 0) ? tile[rb + 80] : 0.0f;   // class 80 only exists for h=0

        // ---- row max (exact, order-free) ----
        float mx = v[0];
        #pragma unroll
        for (int m = 1; m < 40; ++m) mx = fmaxf(mx, v[m]);
        mx = fmaxf(mx, (h == 0) ? v[40] : v[0]);
        float om = __shfl_xor(mx, 1);
        float mrow = fmaxf(mx, om);

        // ---- exps (op-identical to reference kernel) ----
        #pragma unroll
        for (int m = 0; m < 40; ++m) v[m] = expf(v[m] - mrow);
        v[40] = (h == 0) ? expf(v[40] - mrow) : 0.0f;

        // ---- per-thread bitrev subtree over leaves l = h + 2*b ----
        float stk0 = 0.f, stk1 = 0.f, stk2 = 0.f, stk3 = 0.f, stk4 = 0.f;
        float S = 0.f;
        #pragma unroll
        for (int i = 0; i < 32; ++i) {
            const int b = ((i & 1) << 4) | ((i & 2) << 2) | (i & 4) |
                          ((i & 8) >> 2) | ((i & 16) >> 4);   // bitrev5(i)
            float x = v[b];
            if (b < 8) x += v[b + 32];
            else if (b == 8) x = (h == 0) ? x + v[40] : x;
            if (i & 1) { x = stk0 + x;
              if (i & 2) { x = stk1 + x;
                if (i & 4) { x = stk2 + x;
                  if (i & 8) { x = stk3 + x;
                    if (i & 16) { S = stk4 + x; } else stk4 = x;
                  } else stk3 = x;
                } else stk2 = x;
              } else stk1 = x;
            } else stk0 = x;
        }
        float oS = __shfl_xor(S, 1);
        float s = (h == 0) ? (S + oS) : (oS + S);  // exact top-level association

        // ---- emit: conservative pre-filter, then bit-exact p>0.05 ----
        float eth = 0.0499f * s;                   // 0.2% margin >> fp rounding
        unsigned rowflat = (unsigned)(base + r) * N_CLS + (unsigned)h;
        #pragma unroll
        for (int m = 0; m < 41; ++m) {             // COMPILE-TIME v[] index only
            float e = v[m];
            if ((m + h) != 0 && e > eth) {         // skip background (h=0,m=0)
                float p = e / s;                   // identical division
                if (p > SCORE_TH) {
                    unsigned fb = __float_as_uint(p);
                    atomicAdd(&lh[(fb >> 19) - GH_BASE], 1u);
                    u64 key = ((u64)fb << 32) | (u64)(0xFFFFFFu - (rowflat + 2u * (unsigned)m));
                    unsigned pos = atomicAdd(&lcnt, 1u);
                    if (pos < CBUF_CAP) cbuf[pos] = key;
                    else { unsigned gp = atomicAdd(cnt, 1u); if (gp < LISTCAP) sel[gp] = key; }
                }
            }
        }
    }
    __syncthreads();
    unsigned* gh = ghist + (blockIdx.x & (GH_REP - 1)) * 128;
    for (int i = tid; i < 128; i += 256) {
        unsigned vv = lh[i];
        if (vv) atomicAdd(&gh[i], vv);
    }
    unsigned total = lcnt; if (total > CBUF_CAP) total = CBUF_CAP;
    if (tid == 0) gbase = atomicAdd(cnt, total);
    __syncthreads();
    unsigned gb = gbase;
    for (unsigned i = tid; i < total; i += 256) {
        unsigned gp = gb + i;
        if (gp < LISTCAP) sel[gp] = cbuf[i];
    }
}

// ------- K2: round-16 k_tail VERBATIM (62.2us measured) -------
// P0/PF/tb/PR from r14; PC masks spread over ALL 128 blocks (8-box slice
// each); last tickC arrival runs the verified Gauss-Seidel-over-words NMS.
__global__ __launch_bounds__(1024) void k_tail(
        char* __restrict__ ws, const float* __restrict__ boxes,
        float* __restrict__ out) {
    unsigned* cnt   = (unsigned*)(ws + OFF_CNT);
    unsigned* cnt2  = (unsigned*)(ws + OFF_CNT2);
    unsigned* tickA = (unsigned*)(ws + OFF_TICKA);
    unsigned* tickR = (unsigned*)(ws + OFF_TICKR);
    unsigned* tickC = (unsigned*)(ws + OFF_TICKC);
    unsigned* ghist = (unsigned*)(ws + OFF_GH);
    unsigned* rhist = (unsigned*)(ws + OFF_RH);
    u64*      sel   = (u64*)(ws + OFF_SEL);
    u64*      sel2  = (u64*)(ws + OFF_SEL2);
    u64*      boxB  = (u64*)(ws + OFF_BOX);
    unsigned* scrB  = (unsigned*)(ws + OFF_SCORE);
    unsigned* clsB  = (unsigned*)(ws + OFF_CLS);
    u64*      mask  = (u64*)(ws + OFF_MASK);

    __shared__ unsigned scu[1024], sfu[1024];
    __shared__ union {
        unsigned lhist[1024];               // PF local refine hist (4 KB)
        struct {                            // box cache, bank-padded SoA
            float x1[PADK], y1[PADK], x2[PADK], y2[PADK];
            int cls[PADK]; unsigned sc[PADK];
        } c;                                // ~24.4 KB
    } shu;
    __shared__ u64 words[16];
    __shared__ int swB;
    __shared__ unsigned swCA, stk, stb;

    int tid = threadIdx.x, ln = tid & 63;
    unsigned nb = gridDim.x;

    // -------- P0 (every block, redundant): coarse B, CA from ghist --------
    if (tid < 128) {
        unsigned c = 0;
        #pragma unroll
        for (int rr = 0; rr < GH_REP; ++rr) c += ghist[rr * 128 + tid];  // cross-kernel
        scu[tid] = c; sfu[tid] = c;
    }
    if (tid == 0) swB = -1;
    __syncthreads();
    #pragma unroll
    for (int off = 1; off < 128; off <<= 1) {
        unsigned a = 0;
        if (tid < 128) a = (tid + off < 128) ? sfu[tid + off] : 0u;
        __syncthreads();
        if (tid < 128) sfu[tid] += a;
        __syncthreads();
    }
    if (tid == 0) swCA = sfu[0];                   // total (B<0 fallback)
    __syncthreads();
    if (tid < 128) {
        unsigned incl = sfu[tid], excl = incl - scu[tid];
        if (excl < TOPK && incl >= TOPK) { swB = tid; swCA = excl; }
    }
    __syncthreads();
    int B = swB;
    unsigned CA = swCA;
    unsigned M = *cnt; if (M > LISTCAP) M = LISTCAP;   // cross-kernel plain load
    unsigned stride = nb * 1024u;
    unsigned tbc = (B < 0) ? 0u : ((unsigned)(B + GH_BASE) << 19);  // coarse floor
    unsigned Bbits = (unsigned)(B + GH_BASE);

    // -------- PF: ONE pass: compact >= coarse floor AND refine-histogram.
    // Per-wave cnt2 atomics; NO block barriers inside the loop (r13 lesson). --------
    shu.lhist[tid] = 0;
    __syncthreads();
    for (unsigned ibase = blockIdx.x * 1024u; ibase < M; ibase += stride) {
        unsigned i = ibase + tid;
        bool act = (i < M);
        u64 key = act ? sel[i] : 0ull;                 // cross-kernel plain load
        unsigned bv = (unsigned)(key >> 32);
        if (act && B >= 0 && (bv >> 19) == Bbits)
            atomicAdd(&shu.lhist[(bv >> 9) & 1023u], 1u);
        bool c = act && (bv >= tbc) && (key != 0ull);
        u64 b = __ballot(c);
        int n = __popcll(b);
        if (n) {
            unsigned wb = 0;
            if (ln == 0) wb = atomicAdd(cnt2, (unsigned)n);
            wb = __shfl(wb, 0);
            if (c) {
                unsigned pos = wb + (unsigned)__popcll(b & ((1ull << ln) - 1ull));
                if (pos < CAP2) agent_store_u64(&sel2[pos], key);
            }
        }
    }
    __syncthreads();
    { unsigned vv = shu.lhist[tid]; if (vv) atomicAdd(&rhist[tid], vv); }
    __syncthreads();
    drain_vm();                                        // sel2 + rhist acked
    if (tid == 0) {
        atomicAdd(tickA, 1u);
        unsigned v;
        do { __builtin_amdgcn_s_sleep(2); v = agent_load_u32(tickA); } while (v < nb);
    }
    __syncthreads();

    // -------- tb (every block, redundant): suffix-scan rhist -> exact 512-ULP --------
    unsigned tb = 0;
    {
        unsigned c = (B >= 0) ? agent_load_u32(&rhist[tid]) : 0u;
        scu[tid] = c; sfu[tid] = c;
        if (tid == 0) stb = 0;
        __syncthreads();
        #pragma unroll
        for (int off = 1; off < 1024; off <<= 1) {
            unsigned a = (tid + off < 1024) ? sfu[tid + off] : 0u;
            __syncthreads();
            sfu[tid] += a;
            __syncthreads();
        }
        unsigned incl = sfu[tid], excl = incl - scu[tid];
        if (B >= 0 && CA + excl < TOPK && CA + incl >= TOPK)
            stb = ((unsigned)(B + GH_BASE) << 19) | ((unsigned)tid << 9);
        __syncthreads();
        tb = stb;                                      // 0 when B<0: keep all
    }

    // ---------------- PR: wave-per-key rank + decode (keys >= tb only) ----------------
    {
        unsigned S = agent_load_u32(cnt2); if (S > CAP2) S = CAP2;
        unsigned slot = blockIdx.x * 16u + (unsigned)(tid >> 6);
        unsigned nslots = nb * 16u;                    // 2048 wave-slots
        unsigned lim = (S > TOPK) ? S : TOPK;
        for (unsigned k = slot; k < lim; k += nslots) {
            if (k < S) {
                u64 my = agent_load_u64(&sel2[k]);     // wave-uniform key
                if ((unsigned)(my >> 32) < tb) continue;   // below exact threshold
                unsigned rk = 0;
                for (unsigned j = ln; j < S; j += 64)  // coalesced 512B/wave
                    rk += (agent_load_u64(&sel2[j]) > my) ? 1u : 0u;
                #pragma unroll
                for (int off = 32; off > 0; off >>= 1) rk += __shfl_xor(rk, off);
                if (ln == 0 && rk < TOPK) {
                    float sc = __uint_as_float((unsigned)(my >> 32));
                    unsigned fi = 0xFFFFFFu - (unsigned)(my & 0xFFFFFFFFull);
                    unsigned prop = fi / N_CLS;
                    int cls = (int)(fi - prop * N_CLS);
                    const float* bx = boxes + (size_t)prop * 4;
                    float x1 = fminf(fmaxf(bx[0], 0.0f), IMG_W - 1.0f);
                    float y1 = fminf(fmaxf(bx[1], 0.0f), IMG_H - 1.0f);
                    float x2 = fminf(fmaxf(bx[2], 0.0f), IMG_W - 1.0f);
                    float y2 = fminf(fmaxf(bx[3], 0.0f), IMG_H - 1.0f);
                    agent_store_u64(&boxB[rk * 2],
                        ((u64)__float_as_uint(y1) << 32) | __float_as_uint(x1));
                    agent_store_u64(&boxB[rk * 2 + 1],
                        ((u64)__float_as_uint(y2) << 32) | __float_as_uint(x2));
                    agent_store_u32(&scrB[rk], __float_as_uint(sc));
                    agent_store_u32(&clsB[rk], (unsigned)cls);
                }
            } else if (ln == 0) {                      // k in [S, TOPK): B<0 defaults
                agent_store_u64(&boxB[k * 2], 0ull);
                agent_store_u64(&boxB[k * 2 + 1], 0ull);
                agent_store_u32(&scrB[k], 0u);
                agent_store_u32(&clsB[k], (unsigned)-1);
            }
        }
    }
    __syncthreads();
    drain_vm();
    if (tid == 0) {
        atomicAdd(tickR, 1u);
        unsigned v;
        do { __builtin_amdgcn_s_sleep(2); v = agent_load_u32(tickR); } while (v < nb);
    }
    __syncthreads();

    // -------- PC (ALL blocks): coop-load boxes to LDS; 8-box mask slice --------
    if (tid < TOPK) {
        u64 a = agent_load_u64(&boxB[tid * 2]);
        u64 b = agent_load_u64(&boxB[tid * 2 + 1]);
        int ip = ipad(tid);
        shu.c.x1[ip] = __uint_as_float((unsigned)a);
        shu.c.y1[ip] = __uint_as_float((unsigned)(a >> 32));
        shu.c.x2[ip] = __uint_as_float((unsigned)b);
        shu.c.y2[ip] = __uint_as_float((unsigned)(b >> 32));
        shu.c.cls[ip] = (int)agent_load_u32(&clsB[tid]);
        shu.c.sc[ip]  = agent_load_u32(&scrB[tid]);
    }
    __syncthreads();
    if (tid < 128) {
        int i = blockIdx.x * 8 + (tid >> 4), w = tid & 15;
        if (i < TOPK) {
            int ip = ipad(i);
            float x1 = shu.c.x1[ip], y1 = shu.c.y1[ip];
            float x2 = shu.c.x2[ip], y2 = shu.c.y2[ip];
            int ci = shu.c.cls[ip];
            float ai = (x2 - x1) * (y2 - y1);
            u64 m = 0;
            int jbase = w << 6;
            for (int jj = 0; jj < 64; jj++) {
                int j = jbase + jj;
                if (j >= TOPK) break;
                int jp = ipad(j);                      // stride-65: conflict-free
                float u1 = shu.c.x1[jp], w1 = shu.c.y1[jp];
                float u2 = shu.c.x2[jp], w2 = shu.c.y2[jp];
                float aj = (u2 - u1) * (w2 - w1);
                float ww = fmaxf(fminf(x2, u2) - fmaxf(x1, u1), 0.0f);
                float hh = fmaxf(fminf(y2, w2) - fmaxf(y1, w1), 0.0f);
                float inter = ww * hh;
                float iou = inter / (ai + aj - inter + 1e-9f);
                if (iou > 0.5f && ci == shu.c.cls[jp]) m |= (1ull << jj);
            }
            agent_store_u64(&mask[(size_t)i * 16 + w], m);
        }
    }
    __syncthreads();
    drain_vm();
    if (tid == 0) stk = atomicAdd(tickC, 1u);
    __syncthreads();
    if (stk != nb - 1) return;                         // last arrival runs NMS

    // -------- winner: Gauss-Seidel-over-words NMS (r15-verified logic) --------
    u64 row[16];
    #pragma unroll
    for (int w = 0; w < 16; w++)
        row[w] = (tid < TOPK) ? agent_load_u64(&mask[(size_t)tid * 16 + w]) : 0ull;
    int wvv = tid >> 6;
    int myip = ipad(tid < TOPK ? tid : 0);
    bool valid = (tid < TOPK) && (__uint_as_float(shu.c.sc[myip]) > 0.0f);
    u64 lowmask = (1ull << ln) - 1ull;
    bool keep = false;
    for (int w = 0; w < 16; ++w) {
        if (wvv == w) {
            u64 ext = 0;
            for (int u = 0; u < w; ++u) ext |= row[u] & words[u];   // finalized
            bool k = valid && (ext == 0ull);
            u64 K = __ballot(k), Kp;
            int guard = 0;
            do {
                Kp = K;
                k = valid && (ext == 0ull) && ((row[w] & Kp & lowmask) == 0ull);
                K = __ballot(k);
            } while (K != Kp && ++guard < 64);
            if (ln == 0) words[w] = K;
            keep = k;
        }
        __syncthreads();                               // publish words[w]
    }

    if (tid < TOPK) {
        float sc = __uint_as_float(shu.c.sc[myip]);
        out[tid * 5 + 0] = keep ? shu.c.x1[myip] : 0.0f;
        out[tid * 5 + 1] = keep ? shu.c.y1[myip] : 0.0f;
        out[tid * 5 + 2] = keep ? shu.c.x2[myip] : 0.0f;
        out[tid * 5 + 3] = keep ? shu.c.y2[myip] : 0.0f;
        out[tid * 5 + 4] = keep ? sc : 0.0f;
    }
}

extern "C" void kernel_launch(void* const* d_in, const int* in_sizes, int n_in,
                              void* d_out, int out_size, void* d_ws, size_t ws_size,
                              hipStream_t stream) {
    const float* logits = (const float*)d_in[0];
    const float* boxes  = (const float*)d_in[1];
    float* out = (float*)d_out;
    int nrows = in_sizes[0] / N_CLS;   // 200000

    char* w = (char*)d_ws;
    unsigned* cnt   = (unsigned*)(w + OFF_CNT);
    unsigned* ghist = (unsigned*)(w + OFF_GH);
    u64* sel        = (u64*)(w + OFF_SEL);

    hipMemsetAsync(w, 0, MEMSET_BYTES, stream);

    int nblk = (nrows + ROWS_PER_BLK - 1) / ROWS_PER_BLK;   // 1563
    k_pass1<<<nblk, 256, 0, stream>>>(logits, nrows, sel, cnt, ghist);
    k_tail<<<TAIL_BLOCKS, 1024, 0, stream>>>(w, boxes, out);
}